// Round 13
// baseline (231.983 us; speedup 1.0000x reference)
//
#include <hip/hip_runtime.h>
#include <hip/hip_bf16.h>

#define B_  32
#define T_  2048
#define DH_ 1024
#define DS_ 1024
#define A_  512
#define M_  (B_ * T_)   // 65536

typedef __attribute__((ext_vector_type(8))) short bf16x8;
typedef __attribute__((ext_vector_type(4))) float f32x4;

__device__ __forceinline__ unsigned short f2bf(float f) {
    union { float f; unsigned u; } v; v.f = f;
    unsigned r = 0x7FFFu + ((v.u >> 16) & 1u);
    return (unsigned short)((v.u + r) >> 16);
}
__device__ __forceinline__ float fast_tanh(float x) {
    float cx = fminf(fmaxf(x, -9.f), 9.f);
    float e2 = __expf(2.f * cx);
    return (e2 - 1.f) / (e2 + 1.f);
}
__device__ __forceinline__ unsigned pack_bf2(float lo, float hi) {
    union { float f; unsigned u; } a, b;
    a.f = lo; b.f = hi;
    return __builtin_amdgcn_perm(b.u + 0x8000u, a.u + 0x8000u, 0x07060302u);
}

// ---- zero e [M_] ---------------------------------------------------------
__global__ void zero_e(float* __restrict__ e) {
    e[blockIdx.x * 256 + threadIdx.x] = 0.f;
}

// ---- U_t[a][k] = bf16(U_a[k][a]) -----------------------------------------
__global__ void prep_ut(const float* __restrict__ U, unsigned short* __restrict__ Ut) {
    int o = blockIdx.x * 256 + threadIdx.x;
    int a = o >> 10, k = o & (DH_ - 1);
    Ut[o] = f2bf(U[k * A_ + a]);
}

// ---- Ws[b][a] = s[b,:] . W_a[:,a]  (k-split 4-way + LDS reduce) ----------
__global__ void ws_gemv2(const float* __restrict__ s, const float* __restrict__ W,
                         float* __restrict__ Ws) {
    __shared__ float red[4][64];
    const int blk = blockIdx.x;
    const int b = blk >> 3, a0 = (blk & 7) * 64;
    const int tid = threadIdx.x;
    const int a = a0 + (tid & 63), kq = tid >> 6;
    const float* sp = s + b * DS_ + kq * 256;
    const float* wp = W + (size_t)(kq * 256) * A_ + a;
    float acc = 0.f;
#pragma unroll 8
    for (int k = 0; k < 256; ++k) acc += sp[k] * wp[(size_t)k * A_];
    red[kq][tid & 63] = acc;
    __syncthreads();
    if (tid < 64)
        Ws[b * A_ + a0 + tid] = red[0][tid] + red[1][tid] + red[2][tid] + red[3][tid];
}

// ---- main GEMM: BM=256, BN=256, BK=64, 8 waves (2Mx4N, wave 128x64),
// 16 K-steps/block, 512 blocks total (8192 device-steps = 1/4 of R11).
// 64 MFMA per wave per single s_barrier. A: f32 reg-staged, loads issued
// BEFORE B-gls (R11 vmcnt ordering), perm-packed after MFMA into swizzled
// As. B: gls w=16, pre-swizzled source, 2-buf. 128 KB LDS, 1 block/CU.
__global__ void __launch_bounds__(512, 1)
gemm_v6(const float* __restrict__ h,
        const unsigned short* __restrict__ Ut,
        const float* __restrict__ Ws, const float* __restrict__ va,
        float* __restrict__ e) {
    __shared__ unsigned short As[2][256][64];   // 64 KB
    __shared__ unsigned short Bs[2][256][64];   // 64 KB

    const int tid = threadIdx.x;
    // XCD-chunk swizzle: nwg = 512, 64 wg/XCD; tn-pair of A-panel same XCD
    const int bid0 = blockIdx.x;
    const int bid = (bid0 & 7) * 64 + (bid0 >> 3);
    const int tn = bid & 1, tm = bid >> 1;
    const int rowBase = tm * 256, nBase = tn * 256;

    const int lane = tid & 63;
    const int wid = tid >> 6;                   // 8 waves: 2(M) x 4(N)
    const int wm = wid >> 2, wn = wid & 3;      // wave tile 128(m) x 64(n)
    const int lr = lane & 15, kg = lane >> 4;

    // A staging: thread covers row ar = tid>>1, f32 col-half ch = tid&1
    const int ar = tid >> 1;
    const int ach = (tid & 1) * 32;             // f32 col base
    const int agb = (tid & 1) * 4;              // granule base

    f32x4 acc[8][4];
#pragma unroll
    for (int i = 0; i < 8; ++i)
#pragma unroll
        for (int j = 0; j < 4; ++j) acc[i][j] = (f32x4){0.f, 0.f, 0.f, 0.f};

    auto loadA = [&](float4* areg, int tile) {  // 8 loads (issued FIRST)
        const float* hp = h + (size_t)(rowBase + ar) * DH_ + tile * 64 + ach;
#pragma unroll
        for (int j = 0; j < 8; ++j) areg[j] = *(const float4*)(hp + j * 4);
    };
    auto stageB = [&](int buf, int tile) {      // 4 gls
        const int k0 = tile * 64;
#pragma unroll
        for (int j = 0; j < 4; ++j) {
            int byt = j * 8192 + tid * 16;      // byte off in 32 KB tile
            int r = byt >> 7;                   // row 0..255
            int g = ((byt >> 4) & 7) ^ (r & 7); // pre-swizzled source granule
            const unsigned short* gb = Ut + (size_t)(nBase + r) * DH_ + k0 + g * 8;
            __builtin_amdgcn_global_load_lds(
                (const __attribute__((address_space(1))) unsigned int*)gb,
                (__attribute__((address_space(3))) unsigned int*)(&Bs[buf][0][0] + (byt >> 1)),
                16, 0, 0);
        }
    };
    auto packwriteA = [&](const float4* areg, int buf) {
#pragma unroll
        for (int g4 = 0; g4 < 4; ++g4) {
            uint4 u;
            u.x = pack_bf2(areg[2 * g4].x, areg[2 * g4].y);
            u.y = pack_bf2(areg[2 * g4].z, areg[2 * g4].w);
            u.z = pack_bf2(areg[2 * g4 + 1].x, areg[2 * g4 + 1].y);
            u.w = pack_bf2(areg[2 * g4 + 1].z, areg[2 * g4 + 1].w);
            int gs = (agb + g4) ^ (ar & 7);
            *(uint4*)(&As[buf][ar][gs * 8]) = u;
        }
    };

    float4 areg[8];
    const int NT = DH_ / 64;                    // 16 K-steps

    // prologue: A(0) loads first, then B(0) gls; pack waits only on loadA
    loadA(areg, 0);
    __builtin_amdgcn_sched_barrier(0);
    stageB(0, 0);
    __builtin_amdgcn_sched_barrier(0);
    packwriteA(areg, 0);                        // auto vmcnt(4): loadA done
    asm volatile("s_waitcnt vmcnt(0) lgkmcnt(0)" ::: "memory");
    __builtin_amdgcn_s_barrier();
    __builtin_amdgcn_sched_barrier(0);

#pragma unroll 1
    for (int t = 0; t < NT; ++t) {
        const int buf = t & 1;
        const bool more = (t < NT - 1);
        // issue next tile: A loads FIRST (oldest), then B gls
        if (more) {
            loadA(areg, t + 1);
            __builtin_amdgcn_sched_barrier(0);
            stageB(buf ^ 1, t + 1);
            __builtin_amdgcn_sched_barrier(0);
        }

        const unsigned short* Ab = &As[buf][0][0];
        const unsigned short* Bb = &Bs[buf][0][0];

#pragma unroll
        for (int kh = 0; kh < 2; ++kh) {
            bf16x8 bq[4], af[8];
#pragma unroll
            for (int nf = 0; nf < 4; ++nf) {
                int rb = wn * 64 + nf * 16 + lr;
                bq[nf] = *(const bf16x8*)(Bb + rb * 64 + (((kh * 4 + kg) ^ (rb & 7)) * 8));
            }
#pragma unroll
            for (int mi = 0; mi < 8; ++mi) {
                int ra = wm * 128 + mi * 16 + lr;
                af[mi] = *(const bf16x8*)(Ab + ra * 64 + (((kh * 4 + kg) ^ (ra & 7)) * 8));
            }
            asm volatile("s_waitcnt lgkmcnt(0)" ::: "memory");
            __builtin_amdgcn_sched_barrier(0);
            __builtin_amdgcn_s_setprio(1);
#pragma unroll
            for (int mi = 0; mi < 8; ++mi)
#pragma unroll
                for (int nf = 0; nf < 4; ++nf)
                    acc[mi][nf] = __builtin_amdgcn_mfma_f32_16x16x32_bf16(
                        af[mi], bq[nf], acc[mi][nf], 0, 0, 0);
            __builtin_amdgcn_s_setprio(0);
            __builtin_amdgcn_sched_barrier(0);
        }

        if (more) {
            packwriteA(areg, buf ^ 1);          // auto vmcnt(4): B stays in flight
            asm volatile("s_waitcnt vmcnt(0) lgkmcnt(0)" ::: "memory");
            __builtin_amdgcn_s_barrier();
            __builtin_amdgcn_sched_barrier(0);
        }
    }

    // epilogue: e[row] += sum_a tanh(acc + Ws[b][a]) * v[a]
    const int bIdx = rowBase >> 11;
    const float* WsRow = Ws + bIdx * A_;
    float wsv[4], vav[4];
#pragma unroll
    for (int nf = 0; nf < 4; ++nf) {
        int a = nBase + wn * 64 + nf * 16 + lr;
        wsv[nf] = WsRow[a];
        vav[nf] = va[a];
    }
#pragma unroll
    for (int mi = 0; mi < 8; ++mi) {
#pragma unroll
        for (int j = 0; j < 4; ++j) {
            float ssum = 0.f;
#pragma unroll
            for (int nf = 0; nf < 4; ++nf) {
                float x = acc[mi][nf][j] + wsv[nf];
                ssum += fast_tanh(x) * vav[nf];
            }
            ssum += __shfl_xor(ssum, 1);
            ssum += __shfl_xor(ssum, 2);
            ssum += __shfl_xor(ssum, 4);
            ssum += __shfl_xor(ssum, 8);
            if (lr == 0) {
                int row = rowBase + wm * 128 + mi * 16 + kg * 4 + j;
                atomicAdd(&e[row], ssum);
            }
        }
    }
}

// ---- fused softmax + context (f32 h, L3-warm): block = (b, dseg) ---------
__global__ void smax_ctx(const float* __restrict__ e, const float* __restrict__ h,
                         float* __restrict__ c) {
    __shared__ float al[T_];
    __shared__ float red[8];
    __shared__ float part[256];
    const int b = blockIdx.x >> 3, dseg = blockIdx.x & 7;
    const int tid = threadIdx.x;
    const float* ep = e + (size_t)b * T_;

    float4 v0 = ((const float4*)ep)[tid * 2];
    float4 v1 = ((const float4*)ep)[tid * 2 + 1];
    float m = fmaxf(fmaxf(fmaxf(v0.x, v0.y), fmaxf(v0.z, v0.w)),
                    fmaxf(fmaxf(v1.x, v1.y), fmaxf(v1.z, v1.w)));
#pragma unroll
    for (int off = 1; off < 64; off <<= 1) m = fmaxf(m, __shfl_xor(m, off));
    const int wv = tid >> 6;
    if ((tid & 63) == 0) red[wv] = m;
    __syncthreads();
    m = fmaxf(fmaxf(red[0], red[1]), fmaxf(red[2], red[3]));
    float e0 = __expf(v0.x - m), e1 = __expf(v0.y - m);
    float e2 = __expf(v0.z - m), e3 = __expf(v0.w - m);
    float e4 = __expf(v1.x - m), e5 = __expf(v1.y - m);
    float e6 = __expf(v1.z - m), e7 = __expf(v1.w - m);
    float ssum = e0 + e1 + e2 + e3 + e4 + e5 + e6 + e7;
#pragma unroll
    for (int off = 1; off < 64; off <<= 1) ssum += __shfl_xor(ssum, off);
    if ((tid & 63) == 0) red[4 + wv] = ssum;
    al[tid * 8 + 0] = e0; al[tid * 8 + 1] = e1;
    al[tid * 8 + 2] = e2; al[tid * 8 + 3] = e3;
    al[tid * 8 + 4] = e4; al[tid * 8 + 5] = e5;
    al[tid * 8 + 6] = e6; al[tid * 8 + 7] = e7;
    __syncthreads();
    const float inv = 1.f / (red[4] + red[5] + red[6] + red[7]);

    const int d = dseg * 128 + (tid & 127);
    const int th = tid >> 7;
    const float* hp = h + ((size_t)b * T_ + th) * DH_ + d;
    float acc = 0.f;
#pragma unroll 8
    for (int t = 0; t < T_ / 2; ++t)
        acc += al[2 * t + th] * hp[(size_t)(2 * t) * DH_];
    part[tid] = acc;
    __syncthreads();
    if (tid < 128)
        c[(size_t)b * DH_ + dseg * 128 + tid] = (part[tid] + part[tid + 128]) * inv;
}

extern "C" void kernel_launch(void* const* d_in, const int* in_sizes, int n_in,
                              void* d_out, int out_size, void* d_ws, size_t ws_size,
                              hipStream_t stream) {
    const float* s   = (const float*)d_in[0];
    const float* h   = (const float*)d_in[1];
    const float* W_a = (const float*)d_in[2];
    const float* U_a = (const float*)d_in[3];
    const float* v_a = (const float*)d_in[4];
    float* c = (float*)d_out;

    // workspace: e [65536 f32] | Ws [16384 f32] | Ut [524288 bf16]  (~1.3 MB)
    float* e  = (float*)d_ws;
    float* Ws = e + M_;
    unsigned short* Ut = (unsigned short*)(Ws + B_ * A_);

    zero_e<<<M_ / 256, 256, 0, stream>>>(e);
    prep_ut<<<(A_ * DH_) / 256, 256, 0, stream>>>(U_a, Ut);
    ws_gemv2<<<B_ * 8, 256, 0, stream>>>(s, W_a, Ws);
    gemm_v6<<<(M_ / 256) * (A_ / 256), 512, 0, stream>>>(h, Ut, Ws, v_a, e);
    smax_ctx<<<B_ * 8, 256, 0, stream>>>(e, h, c);
}

// Round 14
// 204.988 us; speedup vs baseline: 1.1317x; 1.1317x over previous
//
#include <hip/hip_runtime.h>
#include <hip/hip_bf16.h>

#define B_  32
#define T_  2048
#define DH_ 1024
#define DS_ 1024
#define A_  512
#define M_  (B_ * T_)   // 65536

typedef __attribute__((ext_vector_type(8))) short bf16x8;
typedef __attribute__((ext_vector_type(4))) float f32x4;

__device__ __forceinline__ unsigned short f2bf(float f) {
    union { float f; unsigned u; } v; v.f = f;
    unsigned r = 0x7FFFu + ((v.u >> 16) & 1u);
    return (unsigned short)((v.u + r) >> 16);
}
__device__ __forceinline__ float fast_tanh(float x) {
    float cx = fminf(fmaxf(x, -9.f), 9.f);
    float e2 = __expf(2.f * cx);
    return (e2 - 1.f) / (e2 + 1.f);
}
__device__ __forceinline__ unsigned pack_bf2(float lo, float hi) {
    union { float f; unsigned u; } a, b;
    a.f = lo; b.f = hi;
    return __builtin_amdgcn_perm(b.u + 0x8000u, a.u + 0x8000u, 0x07060302u);
}

// ---- U_t[a][k] = bf16(U_a[k][a]) -----------------------------------------
__global__ void prep_ut(const float* __restrict__ U, unsigned short* __restrict__ Ut) {
    int o = blockIdx.x * 256 + threadIdx.x;
    int a = o >> 10, k = o & (DH_ - 1);
    Ut[o] = f2bf(U[k * A_ + a]);
}

// ---- Ws[b][a] = s[b,:] . W_a[:,a]  (k-split 4-way + LDS reduce) ----------
__global__ void ws_gemv2(const float* __restrict__ s, const float* __restrict__ W,
                         float* __restrict__ Ws) {
    __shared__ float red[4][64];
    const int blk = blockIdx.x;
    const int b = blk >> 3, a0 = (blk & 7) * 64;
    const int tid = threadIdx.x;
    const int a = a0 + (tid & 63), kq = tid >> 6;
    const float* sp = s + b * DS_ + kq * 256;
    const float* wp = W + (size_t)(kq * 256) * A_ + a;
    float acc = 0.f;
#pragma unroll 8
    for (int k = 0; k < 256; ++k) acc += sp[k] * wp[(size_t)k * A_];
    red[kq][tid & 63] = acc;
    __syncthreads();
    if (tid < 64)
        Ws[b * A_ + a0 + tid] = red[0][tid] + red[1][tid] + red[2][tid] + red[3][tid];
}

// ---- main GEMM: BM=128, BN=512 (FULL A width), BK=32, 8 waves (2Mx4N,
// wave 64x128). Each block computes COMPLETE e-rows: h read ONCE device-
// wide (the R13 diagnosis: prior variants were L2/L3-BW-bound on 2-4x h
// re-reads). B (whole Ut K-slice) re-read from L2 (1 MB resident).
// A: f32 reg-staged (loads issued first), perm-packed into swizzled As.
// B: gls w=16 pre-swizzled, 2-buf. No atomics: in-block reduce via As
// alias -> direct e stores. 80 KB LDS; acc 128 VGPR -> 8 waves/CU.
__global__ void __launch_bounds__(512, 2)
gemm_bn512(const float* __restrict__ h,
           const unsigned short* __restrict__ Ut,
           const float* __restrict__ Ws, const float* __restrict__ va,
           float* __restrict__ e) {
    __shared__ unsigned short As[2][128][32];   // 16 KB
    __shared__ unsigned short Bs[2][512][32];   // 64 KB

    const int tid = threadIdx.x;
    const int tm = blockIdx.x;                  // 512 blocks, no tn
    const int rowBase = tm * 128;

    const int lane = tid & 63;
    const int wid = tid >> 6;                   // 8 waves: 2(M) x 4(N)
    const int wm = wid >> 2, wn = wid & 3;      // wave tile 64(m) x 128(n)
    const int lr = lane & 15, kg = lane >> 4;
    const int gsw16 = (kg ^ ((lr >> 1) & 3)) * 8;   // lane-uniform read swizzle

    // A staging: thread -> row ar = tid>>2, logical granule lg = tid&3 (8 f32)
    const int ar = tid >> 2;
    const int alg = tid & 3;

    f32x4 acc[4][8];
#pragma unroll
    for (int i = 0; i < 4; ++i)
#pragma unroll
        for (int j = 0; j < 8; ++j) acc[i][j] = (f32x4){0.f, 0.f, 0.f, 0.f};

    auto loadA = [&](float4* areg, int t) {     // 2 loads (issue FIRST)
        const float* hp = h + (size_t)(rowBase + ar) * DH_ + t * 32 + alg * 8;
        areg[0] = *(const float4*)(hp);
        areg[1] = *(const float4*)(hp + 4);
    };
    auto stageB = [&](int buf, int t) {         // 4 gls
        const int k0 = t * 32;
#pragma unroll
        for (int j = 0; j < 4; ++j) {
            int byt = j * 8192 + tid * 16;      // byte off in 32 KB tile
            int r = byt >> 6;                   // row 0..511
            int g = ((byt >> 4) & 3) ^ ((r >> 1) & 3);
            const unsigned short* gb = Ut + (size_t)r * DH_ + k0 + g * 8;
            __builtin_amdgcn_global_load_lds(
                (const __attribute__((address_space(1))) unsigned int*)gb,
                (__attribute__((address_space(3))) unsigned int*)(&Bs[buf][0][0] + (byt >> 1)),
                16, 0, 0);
        }
    };
    auto packwriteA = [&](const float4* areg, int buf) {
        uint4 u;
        u.x = pack_bf2(areg[0].x, areg[0].y);
        u.y = pack_bf2(areg[0].z, areg[0].w);
        u.z = pack_bf2(areg[1].x, areg[1].y);
        u.w = pack_bf2(areg[1].z, areg[1].w);
        int p = alg ^ ((ar >> 1) & 3);
        *(uint4*)((char*)&As[buf][0][0] + ar * 64 + p * 16) = u;
    };

    float4 areg[2];
    const int NT = DH_ / 32;                    // 32 K-steps

    // prologue
    loadA(areg, 0);
    __builtin_amdgcn_sched_barrier(0);
    stageB(0, 0);
    __builtin_amdgcn_sched_barrier(0);
    packwriteA(areg, 0);                        // auto-wait drains loadA only
    asm volatile("s_waitcnt vmcnt(0) lgkmcnt(0)" ::: "memory");
    __builtin_amdgcn_s_barrier();
    __builtin_amdgcn_sched_barrier(0);

#pragma unroll 1
    for (int t = 0; t < NT; ++t) {
        const int buf = t & 1;
        const bool more = (t < NT - 1);
        if (more) {
            loadA(areg, t + 1);                 // FIRST -> oldest
            __builtin_amdgcn_sched_barrier(0);
            stageB(buf ^ 1, t + 1);
            __builtin_amdgcn_sched_barrier(0);
        }

        const unsigned short* Ab = &As[buf][0][0];
        const unsigned short* Bb = &Bs[buf][0][0];
        bf16x8 af[4], bq[8];
#pragma unroll
        for (int nf = 0; nf < 8; ++nf)
            bq[nf] = *(const bf16x8*)(Bb + (wn * 128 + nf * 16 + lr) * 32 + gsw16);
#pragma unroll
        for (int mi = 0; mi < 4; ++mi)
            af[mi] = *(const bf16x8*)(Ab + (wm * 64 + mi * 16 + lr) * 32 + gsw16);
        asm volatile("s_waitcnt lgkmcnt(0)" ::: "memory");
        __builtin_amdgcn_sched_barrier(0);

        __builtin_amdgcn_s_setprio(1);
#pragma unroll
        for (int mi = 0; mi < 4; ++mi)
#pragma unroll
            for (int nf = 0; nf < 8; ++nf)
                acc[mi][nf] = __builtin_amdgcn_mfma_f32_16x16x32_bf16(
                    af[mi], bq[nf], acc[mi][nf], 0, 0, 0);
        __builtin_amdgcn_s_setprio(0);
        __builtin_amdgcn_sched_barrier(0);

        if (more) {
            packwriteA(areg, buf ^ 1);          // auto vmcnt: loadA drained, gls flies
            asm volatile("s_waitcnt vmcnt(0) lgkmcnt(0)" ::: "memory");
            __builtin_amdgcn_s_barrier();
            __builtin_amdgcn_sched_barrier(0);
        }
    }
    __syncthreads();                            // all frag reads done (As reuse next)

    // epilogue: x = acc + Ws[b][a]; partial[row][wn] = sum_a' tanh(x)*v[a']
    const int bIdx = rowBase >> 11;
    const float* WsRow = Ws + bIdx * A_;
    float wsv[8], vav[8];
#pragma unroll
    for (int nf = 0; nf < 8; ++nf) {
        int a = wn * 128 + nf * 16 + lr;
        wsv[nf] = WsRow[a];
        vav[nf] = va[a];
    }
    float* pf = (float*)&As[0][0][0];           // [128][4] partials (alias As)
#pragma unroll
    for (int mi = 0; mi < 4; ++mi) {
#pragma unroll
        for (int j = 0; j < 4; ++j) {
            float ssum = 0.f;
#pragma unroll
            for (int nf = 0; nf < 8; ++nf) {
                float x = acc[mi][nf][j] + wsv[nf];
                ssum += fast_tanh(x) * vav[nf];
            }
            ssum += __shfl_xor(ssum, 1);
            ssum += __shfl_xor(ssum, 2);
            ssum += __shfl_xor(ssum, 4);
            ssum += __shfl_xor(ssum, 8);
            if (lr == 0) {
                int r = wm * 64 + mi * 16 + kg * 4 + j;
                pf[r * 4 + wn] = ssum;
            }
        }
    }
    __syncthreads();
    if (tid < 128) {
        float v0 = pf[tid * 4 + 0] + pf[tid * 4 + 1] + pf[tid * 4 + 2] + pf[tid * 4 + 3];
        e[rowBase + tid] = v0;
    }
}

// ---- fused softmax + context (f32 h, L3-warm): block = (b, dseg) ---------
__global__ void smax_ctx(const float* __restrict__ e, const float* __restrict__ h,
                         float* __restrict__ c) {
    __shared__ float al[T_];
    __shared__ float red[8];
    __shared__ float part[256];
    const int b = blockIdx.x >> 3, dseg = blockIdx.x & 7;
    const int tid = threadIdx.x;
    const float* ep = e + (size_t)b * T_;

    float4 v0 = ((const float4*)ep)[tid * 2];
    float4 v1 = ((const float4*)ep)[tid * 2 + 1];
    float m = fmaxf(fmaxf(fmaxf(v0.x, v0.y), fmaxf(v0.z, v0.w)),
                    fmaxf(fmaxf(v1.x, v1.y), fmaxf(v1.z, v1.w)));
#pragma unroll
    for (int off = 1; off < 64; off <<= 1) m = fmaxf(m, __shfl_xor(m, off));
    const int wv = tid >> 6;
    if ((tid & 63) == 0) red[wv] = m;
    __syncthreads();
    m = fmaxf(fmaxf(red[0], red[1]), fmaxf(red[2], red[3]));
    float e0 = __expf(v0.x - m), e1 = __expf(v0.y - m);
    float e2 = __expf(v0.z - m), e3 = __expf(v0.w - m);
    float e4 = __expf(v1.x - m), e5 = __expf(v1.y - m);
    float e6 = __expf(v1.z - m), e7 = __expf(v1.w - m);
    float ssum = e0 + e1 + e2 + e3 + e4 + e5 + e6 + e7;
#pragma unroll
    for (int off = 1; off < 64; off <<= 1) ssum += __shfl_xor(ssum, off);
    if ((tid & 63) == 0) red[4 + wv] = ssum;
    al[tid * 8 + 0] = e0; al[tid * 8 + 1] = e1;
    al[tid * 8 + 2] = e2; al[tid * 8 + 3] = e3;
    al[tid * 8 + 4] = e4; al[tid * 8 + 5] = e5;
    al[tid * 8 + 6] = e6; al[tid * 8 + 7] = e7;
    __syncthreads();
    const float inv = 1.f / (red[4] + red[5] + red[6] + red[7]);

    const int d = dseg * 128 + (tid & 127);
    const int th = tid >> 7;
    const float* hp = h + ((size_t)b * T_ + th) * DH_ + d;
    float acc = 0.f;
#pragma unroll 8
    for (int t = 0; t < T_ / 2; ++t)
        acc += al[2 * t + th] * hp[(size_t)(2 * t) * DH_];
    part[tid] = acc;
    __syncthreads();
    if (tid < 128)
        c[(size_t)b * DH_ + dseg * 128 + tid] = (part[tid] + part[tid + 128]) * inv;
}

extern "C" void kernel_launch(void* const* d_in, const int* in_sizes, int n_in,
                              void* d_out, int out_size, void* d_ws, size_t ws_size,
                              hipStream_t stream) {
    const float* s   = (const float*)d_in[0];
    const float* h   = (const float*)d_in[1];
    const float* W_a = (const float*)d_in[2];
    const float* U_a = (const float*)d_in[3];
    const float* v_a = (const float*)d_in[4];
    float* c = (float*)d_out;

    // workspace: e [65536 f32] | Ws [16384 f32] | Ut [524288 bf16]  (~1.3 MB)
    float* e  = (float*)d_ws;
    float* Ws = e + M_;
    unsigned short* Ut = (unsigned short*)(Ws + B_ * A_);

    prep_ut<<<(A_ * DH_) / 256, 256, 0, stream>>>(U_a, Ut);
    ws_gemv2<<<B_ * 8, 256, 0, stream>>>(s, W_a, Ws);
    gemm_bn512<<<M_ / 128, 512, 0, stream>>>(h, Ut, Ws, v_a, e);
    smax_ctx<<<B_ * 8, 256, 0, stream>>>(e, h, c);
}

// Round 15
// 180.350 us; speedup vs baseline: 1.2863x; 1.1366x over previous
//
#include <hip/hip_runtime.h>
#include <hip/hip_bf16.h>

#define B_  32
#define T_  2048
#define DH_ 1024
#define DS_ 1024
#define A_  512
#define M_  (B_ * T_)   // 65536
#define NCH 16          // t-chunks per batch (128 rows each)

typedef __attribute__((ext_vector_type(8))) short bf16x8;
typedef __attribute__((ext_vector_type(4))) float f32x4;

__device__ __forceinline__ unsigned short f2bf(float f) {
    union { float f; unsigned u; } v; v.f = f;
    unsigned r = 0x7FFFu + ((v.u >> 16) & 1u);
    return (unsigned short)((v.u + r) >> 16);
}
__device__ __forceinline__ float fast_tanh(float x) {
    float cx = fminf(fmaxf(x, -9.f), 9.f);
    float e2 = __expf(2.f * cx);
    return (e2 - 1.f) / (e2 + 1.f);
}
__device__ __forceinline__ unsigned pack_bf2(float lo, float hi) {
    union { float f; unsigned u; } a, b;
    a.f = lo; b.f = hi;
    return __builtin_amdgcn_perm(b.u + 0x8000u, a.u + 0x8000u, 0x07060302u);
}

// ---- U_t[a][k] = bf16(U_a[k][a]) -----------------------------------------
__global__ void prep_ut(const float* __restrict__ U, unsigned short* __restrict__ Ut) {
    int o = blockIdx.x * 256 + threadIdx.x;
    int a = o >> 10, k = o & (DH_ - 1);
    Ut[o] = f2bf(U[k * A_ + a]);
}

// ---- Ws[b][a] = s[b,:] . W_a[:,a]  (k-split 4-way + LDS reduce) ----------
__global__ void ws_gemv2(const float* __restrict__ s, const float* __restrict__ W,
                         float* __restrict__ Ws) {
    __shared__ float red[4][64];
    const int blk = blockIdx.x;
    const int b = blk >> 3, a0 = (blk & 7) * 64;
    const int tid = threadIdx.x;
    const int a = a0 + (tid & 63), kq = tid >> 6;
    const float* sp = s + b * DS_ + kq * 256;
    const float* wp = W + (size_t)(kq * 256) * A_ + a;
    float acc = 0.f;
#pragma unroll 8
    for (int k = 0; k < 256; ++k) acc += sp[k] * wp[(size_t)k * A_];
    red[kq][tid & 63] = acc;
    __syncthreads();
    if (tid < 64)
        Ws[b * A_ + a0 + tid] = red[0][tid] + red[1][tid] + red[2][tid] + red[3][tid];
}

// ---- fused: per-(batch, 128-row chunk): e-GEMM (R14-proven loop) ->
// local softmax (m, l, w) -> partial context from L2-warm h.
// Outputs pm[chunk], pl[chunk], pc[chunk][1024].
__global__ void __launch_bounds__(512, 2)
fused_chunk(const float* __restrict__ h,
            const unsigned short* __restrict__ Ut,
            const float* __restrict__ Ws, const float* __restrict__ va,
            float* __restrict__ pm, float* __restrict__ pl,
            float* __restrict__ pc) {
    __shared__ unsigned short As[2][128][32];   // 16 KB
    __shared__ unsigned short Bs[2][512][32];   // 64 KB

    const int tid = threadIdx.x;
    const int tm = blockIdx.x;                  // 512 = b*16 + chunk
    const int rowBase = tm * 128;

    const int lane = tid & 63;
    const int wid = tid >> 6;                   // 8 waves: 2(M) x 4(N)
    const int wm = wid >> 2, wn = wid & 3;      // wave tile 64(m) x 128(n)
    const int lr = lane & 15, kg = lane >> 4;
    const int gsw16 = (kg ^ ((lr >> 1) & 3)) * 8;

    const int ar = tid >> 2;                    // A-staging row
    const int alg = tid & 3;                    // logical granule (8 f32)

    f32x4 acc[4][8];
#pragma unroll
    for (int i = 0; i < 4; ++i)
#pragma unroll
        for (int j = 0; j < 8; ++j) acc[i][j] = (f32x4){0.f, 0.f, 0.f, 0.f};

    auto loadA = [&](float4* areg, int t) {
        const float* hp = h + (size_t)(rowBase + ar) * DH_ + t * 32 + alg * 8;
        areg[0] = *(const float4*)(hp);
        areg[1] = *(const float4*)(hp + 4);
    };
    auto stageB = [&](int buf, int t) {
        const int k0 = t * 32;
#pragma unroll
        for (int j = 0; j < 4; ++j) {
            int byt = j * 8192 + tid * 16;
            int r = byt >> 6;                   // row 0..511
            int g = ((byt >> 4) & 3) ^ ((r >> 1) & 3);
            const unsigned short* gb = Ut + (size_t)r * DH_ + k0 + g * 8;
            __builtin_amdgcn_global_load_lds(
                (const __attribute__((address_space(1))) unsigned int*)gb,
                (__attribute__((address_space(3))) unsigned int*)(&Bs[buf][0][0] + (byt >> 1)),
                16, 0, 0);
        }
    };
    auto packwriteA = [&](const float4* areg, int buf) {
        uint4 u;
        u.x = pack_bf2(areg[0].x, areg[0].y);
        u.y = pack_bf2(areg[0].z, areg[0].w);
        u.z = pack_bf2(areg[1].x, areg[1].y);
        u.w = pack_bf2(areg[1].z, areg[1].w);
        int p = alg ^ ((ar >> 1) & 3);
        *(uint4*)((char*)&As[buf][0][0] + ar * 64 + p * 16) = u;
    };

    float4 areg[2];
    const int NT = DH_ / 32;

    loadA(areg, 0);
    __builtin_amdgcn_sched_barrier(0);
    stageB(0, 0);
    __builtin_amdgcn_sched_barrier(0);
    packwriteA(areg, 0);
    asm volatile("s_waitcnt vmcnt(0) lgkmcnt(0)" ::: "memory");
    __builtin_amdgcn_s_barrier();
    __builtin_amdgcn_sched_barrier(0);

#pragma unroll 1
    for (int t = 0; t < NT; ++t) {
        const int buf = t & 1;
        const bool more = (t < NT - 1);
        if (more) {
            loadA(areg, t + 1);
            __builtin_amdgcn_sched_barrier(0);
            stageB(buf ^ 1, t + 1);
            __builtin_amdgcn_sched_barrier(0);
        }

        const unsigned short* Ab = &As[buf][0][0];
        const unsigned short* Bb = &Bs[buf][0][0];
        bf16x8 af[4], bq[8];
#pragma unroll
        for (int nf = 0; nf < 8; ++nf)
            bq[nf] = *(const bf16x8*)(Bb + (wn * 128 + nf * 16 + lr) * 32 + gsw16);
#pragma unroll
        for (int mi = 0; mi < 4; ++mi)
            af[mi] = *(const bf16x8*)(Ab + (wm * 64 + mi * 16 + lr) * 32 + gsw16);
        asm volatile("s_waitcnt lgkmcnt(0)" ::: "memory");
        __builtin_amdgcn_sched_barrier(0);

        __builtin_amdgcn_s_setprio(1);
#pragma unroll
        for (int mi = 0; mi < 4; ++mi)
#pragma unroll
            for (int nf = 0; nf < 8; ++nf)
                acc[mi][nf] = __builtin_amdgcn_mfma_f32_16x16x32_bf16(
                    af[mi], bq[nf], acc[mi][nf], 0, 0, 0);
        __builtin_amdgcn_s_setprio(0);
        __builtin_amdgcn_sched_barrier(0);

        if (more) {
            packwriteA(areg, buf ^ 1);
            asm volatile("s_waitcnt vmcnt(0) lgkmcnt(0)" ::: "memory");
            __builtin_amdgcn_s_barrier();
            __builtin_amdgcn_sched_barrier(0);
        }
    }
    __syncthreads();                            // As free for reuse

    // ---- phase 2a: e_r = sum_a tanh(acc + Ws) * v  -> er_s[128] ----------
    float* er_s  = (float*)&As[0][0][0];        // 128 f32
    float* red_s = er_s + 128;                  // 128 f32 scratch
    float* w_s   = er_s + 256;                  // 128 f32 weights
    float* pf    = er_s + 384;                  // 128*4 wave partials

    const int bIdx = rowBase >> 11;
    const float* WsRow = Ws + bIdx * A_;
    float wsv[8], vav[8];
#pragma unroll
    for (int nf = 0; nf < 8; ++nf) {
        int a = wn * 128 + nf * 16 + lr;
        wsv[nf] = WsRow[a];
        vav[nf] = va[a];
    }
#pragma unroll
    for (int mi = 0; mi < 4; ++mi) {
#pragma unroll
        for (int j = 0; j < 4; ++j) {
            float ssum = 0.f;
#pragma unroll
            for (int nf = 0; nf < 8; ++nf) {
                float x = acc[mi][nf][j] + wsv[nf];
                ssum += fast_tanh(x) * vav[nf];
            }
            ssum += __shfl_xor(ssum, 1);
            ssum += __shfl_xor(ssum, 2);
            ssum += __shfl_xor(ssum, 4);
            ssum += __shfl_xor(ssum, 8);
            if (lr == 0) {
                int r = wm * 64 + mi * 16 + kg * 4 + j;
                pf[r * 4 + wn] = ssum;
            }
        }
    }
    __syncthreads();
    if (tid < 128) {
        float v = pf[tid * 4] + pf[tid * 4 + 1] + pf[tid * 4 + 2] + pf[tid * 4 + 3];
        er_s[tid] = v;
        red_s[tid] = v;
    }
    __syncthreads();
    // ---- phase 2b: local max + exp + sum ---------------------------------
    if (tid < 64) red_s[tid] = fmaxf(red_s[tid], red_s[tid + 64]);
    __syncthreads();
    if (tid < 32) red_s[tid] = fmaxf(red_s[tid], red_s[tid + 32]);
    __syncthreads();
    if (tid < 16) red_s[tid] = fmaxf(red_s[tid], red_s[tid + 16]);
    __syncthreads();
    if (tid < 8) red_s[tid] = fmaxf(red_s[tid], red_s[tid + 8]);
    __syncthreads();
    if (tid < 4) red_s[tid] = fmaxf(red_s[tid], red_s[tid + 4]);
    __syncthreads();
    if (tid < 2) red_s[tid] = fmaxf(red_s[tid], red_s[tid + 2]);
    __syncthreads();
    if (tid == 0) red_s[0] = fmaxf(red_s[0], red_s[1]);
    __syncthreads();
    const float mloc = red_s[0];
    __syncthreads();
    if (tid < 128) {
        float w = __expf(er_s[tid] - mloc);
        w_s[tid] = w;
        red_s[tid] = w;
    }
    __syncthreads();
    if (tid < 64) red_s[tid] += red_s[tid + 64];
    __syncthreads();
    if (tid < 32) red_s[tid] += red_s[tid + 32];
    __syncthreads();
    if (tid < 16) red_s[tid] += red_s[tid + 16];
    __syncthreads();
    if (tid < 8) red_s[tid] += red_s[tid + 8];
    __syncthreads();
    if (tid < 4) red_s[tid] += red_s[tid + 4];
    __syncthreads();
    if (tid < 2) red_s[tid] += red_s[tid + 2];
    __syncthreads();
    if (tid == 0) {
        pm[tm] = mloc;
        pl[tm] = red_s[0] + red_s[1];
    }

    // ---- phase 3: partial context c_i[d] = sum_t w_t h[t][d] (L2-warm) ---
    float c0 = 0.f, c1 = 0.f;
    const float* hp = h + (size_t)rowBase * DH_ + tid;
#pragma unroll 4
    for (int t = 0; t < 128; ++t) {
        float w = w_s[t];
        c0 += w * hp[(size_t)t * DH_];
        c1 += w * hp[(size_t)t * DH_ + 512];
    }
    float* pcp = pc + (size_t)tm * DH_;
    pcp[tid] = c0;
    pcp[tid + 512] = c1;
}

// ---- combine: c[b][d] = sum_i exp(m_i-M) c_i[d] / sum_i exp(m_i-M) l_i ---
__global__ void combine(const float* __restrict__ pm, const float* __restrict__ pl,
                        const float* __restrict__ pc, float* __restrict__ c) {
    const int b = blockIdx.x;
    const int tid = threadIdx.x;
    float M = -1e30f;
#pragma unroll
    for (int i = 0; i < NCH; ++i) M = fmaxf(M, pm[b * NCH + i]);
    float L = 0.f;
    float sc[NCH];
#pragma unroll
    for (int i = 0; i < NCH; ++i) {
        sc[i] = __expf(pm[b * NCH + i] - M);
        L += sc[i] * pl[b * NCH + i];
    }
    float a0 = 0.f, a1 = 0.f;
#pragma unroll
    for (int i = 0; i < NCH; ++i) {
        const float* pcp = pc + (size_t)(b * NCH + i) * DH_;
        a0 += sc[i] * pcp[tid];
        a1 += sc[i] * pcp[tid + 512];
    }
    const float inv = 1.f / L;
    c[(size_t)b * DH_ + tid] = a0 * inv;
    c[(size_t)b * DH_ + tid + 512] = a1 * inv;
}

extern "C" void kernel_launch(void* const* d_in, const int* in_sizes, int n_in,
                              void* d_out, int out_size, void* d_ws, size_t ws_size,
                              hipStream_t stream) {
    const float* s   = (const float*)d_in[0];
    const float* h   = (const float*)d_in[1];
    const float* W_a = (const float*)d_in[2];
    const float* U_a = (const float*)d_in[3];
    const float* v_a = (const float*)d_in[4];
    float* c = (float*)d_out;

    // ws: Ws [16384 f32] | Ut [524288 bf16] | pm [512] | pl [512] | pc [512*1024]
    float* Ws = (float*)d_ws;
    unsigned short* Ut = (unsigned short*)(Ws + B_ * A_);
    float* pm = (float*)(Ut + (size_t)A_ * DH_);
    float* pl = pm + B_ * NCH;
    float* pc = pl + B_ * NCH;

    prep_ut<<<(A_ * DH_) / 256, 256, 0, stream>>>(U_a, Ut);
    ws_gemv2<<<B_ * 8, 256, 0, stream>>>(s, W_a, Ws);
    fused_chunk<<<B_ * NCH, 512, 0, stream>>>(h, Ut, Ws, v_a, pm, pl, pc);
    combine<<<B_, 512, 0, stream>>>(pm, pl, pc, c);
}